// Round 8
// baseline (1350.176 us; speedup 1.0000x reference)
//
#include <hip/hip_runtime.h>
#include <hip/hip_bf16.h>

// ---------------------------------------------------------------------------
// WinEncoderTransformer, multi-kernel pipeline, bf16 activations end-to-end.
// R7: (1) FFN fused into one per-block kernel (h in LDS, two 64-row halves,
// peak acc 64; fused +x+LN2, li=1 also fuses final LN -> f32 out). Kills the
// h round-trip (268 MB/layer) and the addln2 pass. (2) GEMM BN templated,
// BN=128 everywhere (halves A re-fetch, 2x MFMA per barrier).
// Geometry: N=128, B=1024, C=256; R = 131072 rows.
// ---------------------------------------------------------------------------

#define RT 131072ull
#define ATT_SCALE 0.17677669529663687f   // 32^-0.5

typedef float f32x4 __attribute__((ext_vector_type(4)));
typedef __bf16 bf16x8 __attribute__((ext_vector_type(8)));
typedef unsigned short u16x8 __attribute__((ext_vector_type(8)));
typedef unsigned short u16x4 __attribute__((ext_vector_type(4)));

__device__ __forceinline__ unsigned short f2bf(float f) {
    unsigned int u = __float_as_uint(f);
    return (unsigned short)((u + 0x7FFFu + ((u >> 16) & 1u)) >> 16);  // RNE
}
__device__ __forceinline__ float bf2f(unsigned short s) {
    return __uint_as_float(((unsigned int)s) << 16);
}

// ---------------------------------------------------------------------------
// weight prep: src [L][K][N] f32 -> dst [L][N][K] bf16 (transposed)
// ---------------------------------------------------------------------------
__global__ __launch_bounds__(256) void wprep(const float* __restrict__ src,
                                             unsigned short* __restrict__ dst,
                                             int K, int N)
{
    __shared__ unsigned short t[32][33];
    int l = blockIdx.z;
    const float* s = src + (size_t)l * K * N;
    unsigned short* d = dst + (size_t)l * K * N;
    int r = threadIdx.x >> 3, c4 = (threadIdx.x & 7) * 4;
    int kb = blockIdx.x * 32, nb = blockIdx.y * 32;
    f32x4 v = *(const f32x4*)(s + (size_t)(kb + r) * N + nb + c4);
    #pragma unroll
    for (int j = 0; j < 4; ++j) t[c4 + j][r] = f2bf(v[j]);
    __syncthreads();
    u16x4 o;
    #pragma unroll
    for (int j = 0; j < 4; ++j) o[j] = t[r][c4 + j];
    *(u16x4*)(d + (size_t)(nb + r) * K + kb + c4) = o;
}

// ---------------------------------------------------------------------------
// cvt: tgt f32 -> x bf16
// ---------------------------------------------------------------------------
__global__ __launch_bounds__(256) void cvt_bf16(const float* __restrict__ src,
                                                unsigned short* __restrict__ dst)
{
    size_t i = ((size_t)blockIdx.x * 256 + threadIdx.x) * 8;
    f32x4 a = *(const f32x4*)(src + i);
    f32x4 b = *(const f32x4*)(src + i + 4);
    u16x8 t;
    #pragma unroll
    for (int j = 0; j < 4; ++j) { t[j] = f2bf(a[j]); t[4 + j] = f2bf(b[j]); }
    *(u16x8*)(dst + i) = t;
}

// ---------------------------------------------------------------------------
// MFMA helpers (proven in R5's passing run): A from swizzled LDS, B from
// global transposed bf16. Swizzle: byte = (row*stride + colbyte) ^ ((row&7)<<4)
// ---------------------------------------------------------------------------
template<int MT, int NT, int KS>
__device__ __forceinline__ void mfma_gemm(const char* As, int astride, int am0,
    const unsigned short* __restrict__ BT, int ldbk, int koff,
    int lr, int lk, f32x4 (&acc)[MT][NT])
{
    #pragma unroll
    for (int s = 0; s < KS; ++s) {
        bf16x8 bfr[NT];
        #pragma unroll
        for (int nt = 0; nt < NT; ++nt)
            bfr[nt] = *(const bf16x8*)(BT + (size_t)(nt * 16 + lr) * ldbk + koff + s * 32 + lk * 8);
        #pragma unroll
        for (int mt = 0; mt < MT; ++mt) {
            int row = am0 + mt * 16 + lr;
            bf16x8 afr = *(const bf16x8*)(As + ((row * astride + s * 64 + lk * 16) ^ ((row & 7) << 4)));
            #pragma unroll
            for (int nt = 0; nt < NT; ++nt)
                acc[mt][nt] = __builtin_amdgcn_mfma_f32_16x16x32_bf16(afr, bfr[nt], acc[mt][nt], 0, 0, 0);
        }
    }
}

template<int MT, int NT, bool RELU>
__device__ __forceinline__ void store_lds(char* Ds, int dstride, int dm0, int dn0,
    const float* bias, int lr, int lk, f32x4 (&acc)[MT][NT])
{
    #pragma unroll
    for (int nt = 0; nt < NT; ++nt) {
        float bv = bias ? bias[nt * 16 + lr] : 0.0f;
        #pragma unroll
        for (int mt = 0; mt < MT; ++mt) {
            #pragma unroll
            for (int j = 0; j < 4; ++j) {
                int row = dm0 + mt * 16 + lk * 4 + j;
                int col = dn0 + nt * 16 + lr;
                float v = acc[mt][nt][j] + bv;
                if (RELU) v = fmaxf(v, 0.0f);
                *(unsigned short*)(Ds + ((row * dstride + col * 2) ^ ((row & 7) << 4))) = f2bf(v);
            }
        }
    }
}

// ---------------------------------------------------------------------------
// GEMM: C[M x N] = A[M x K] @ BT[N x K]^T (+bias)(+relu), bf16 in/out, MFMA.
// BM=128, BN templated (64/128), BK=64, 256 threads (2x2 waves).
// ---------------------------------------------------------------------------
template<int BN, bool BIAS, bool RELU>
__global__ __launch_bounds__(256) void gemm_bb(
    const unsigned short* __restrict__ A, int lda,
    const unsigned short* __restrict__ BT,
    const float* __restrict__ bias,
    unsigned short* __restrict__ C, int ldc, int K)
{
    constexpr int NT = BN / 32;
    __shared__ __align__(16) char As[128 * 128];
    __shared__ __align__(16) char Bs[BN * 128];

    const int tid = threadIdx.x;
    const size_t m0 = (size_t)blockIdx.x * 128;
    const int n0 = blockIdx.y * BN;
    const int w = tid >> 6, l = tid & 63;
    const int lr = l & 15, lk = l >> 4;
    const int wm = w >> 1, wn = w & 1;

    f32x4 acc[4][NT] = {};

    for (int k0 = 0; k0 < K; k0 += 64) {
        #pragma unroll
        for (int i = 0; i < 4; ++i) {
            int cid = tid + i * 256, row = cid >> 3, kc = cid & 7;
            u16x8 t = *(const u16x8*)(A + (m0 + row) * lda + k0 + kc * 8);
            *(u16x8*)(As + ((row * 128 + kc * 16) ^ ((row & 7) << 4))) = t;
        }
        #pragma unroll
        for (int i = 0; i < BN / 32; ++i) {
            int fid = tid + i * 256, row = fid >> 3, kc = fid & 7;
            u16x8 t = *(const u16x8*)(BT + (size_t)(n0 + row) * K + k0 + kc * 8);
            *(u16x8*)(Bs + ((row * 128 + kc * 16) ^ ((row & 7) << 4))) = t;
        }
        __syncthreads();
        #pragma unroll
        for (int s = 0; s < 2; ++s) {
            bf16x8 bfr[NT];
            #pragma unroll
            for (int nt = 0; nt < NT; ++nt) {
                int r = wn * (BN / 2) + nt * 16 + lr;
                bfr[nt] = *(const bf16x8*)(Bs + ((r * 128 + s * 64 + lk * 16) ^ ((r & 7) << 4)));
            }
            #pragma unroll
            for (int mt = 0; mt < 4; ++mt) {
                int r = wm * 64 + mt * 16 + lr;
                bf16x8 afr = *(const bf16x8*)(As + ((r * 128 + s * 64 + lk * 16) ^ ((r & 7) << 4)));
                #pragma unroll
                for (int nt = 0; nt < NT; ++nt)
                    acc[mt][nt] = __builtin_amdgcn_mfma_f32_16x16x32_bf16(afr, bfr[nt], acc[mt][nt], 0, 0, 0);
            }
        }
        __syncthreads();
    }
    #pragma unroll
    for (int nt = 0; nt < NT; ++nt) {
        int col = n0 + wn * (BN / 2) + nt * 16 + lr;
        float bv = BIAS ? bias[col] : 0.0f;
        #pragma unroll
        for (int mt = 0; mt < 4; ++mt) {
            #pragma unroll
            for (int j = 0; j < 4; ++j) {
                size_t row = m0 + (size_t)(wm * 64 + mt * 16 + lk * 4 + j);
                float v = acc[mt][nt][j] + bv;
                if (RELU) v = fmaxf(v, 0.0f);
                C[row * ldc + col] = f2bf(v);
            }
        }
    }
}

// ---------------------------------------------------------------------------
// Fused FFN: per 128-row block, two 64-row halves:
//   stage x half -> h = relu(x@W1T+b1) in LDS -> f = h@W2T+b2 in LDS
//   -> LN2(x+f) -> x bf16 (TAIL=false) or LN2 then LNf -> out f32 (TAIL=true)
// 512 threads (8 waves). LDS: xh 32K | hs 64K | fs 32K = 128 KB dynamic.
// Peak acc = 64 regs (hidden phase) — fits the 128-VGPR budget, no spill.
// ---------------------------------------------------------------------------
template<bool TAIL>
__global__ __launch_bounds__(512) void ffn_fused(
    const unsigned short* __restrict__ x,
    const unsigned short* __restrict__ tW1,   // [512][256] this layer
    const unsigned short* __restrict__ tW2,   // [256][512] this layer
    const float* __restrict__ b1, const float* __restrict__ b2,
    const float* __restrict__ g, const float* __restrict__ b,     // ln2
    const float* __restrict__ gf, const float* __restrict__ bf,   // final ln
    unsigned short* __restrict__ xout, float* __restrict__ fout)
{
    extern __shared__ char smem[];
    char* xh = smem;            // 64 rows x 512 B (256 bf16), swizzled
    char* hs = smem + 32768;    // 64 rows x 1024 B (512 bf16), swizzled
    char* fs = smem + 98304;    // 64 rows x 512 B, swizzled

    const int tid = threadIdx.x;
    const int w = tid >> 6, l = tid & 63;
    const int lr = l & 15, lk = l >> 4;
    const size_t rbase = (size_t)blockIdx.x * 128;

    #pragma unroll
    for (int half = 0; half < 2; ++half) {
        const size_t r0 = rbase + half * 64;
        // ---- stage x half: 64 x 256 bf16 ----
        #pragma unroll
        for (int i = 0; i < 4; ++i) {
            int cid = tid + i * 512, row = cid >> 5, c8 = (cid & 31) * 8;
            u16x8 t = *(const u16x8*)(x + (r0 + row) * 256 + c8);
            *(u16x8*)(xh + ((row * 512 + c8 * 2) ^ ((row & 7) << 4))) = t;
        }
        __syncthreads();
        // ---- hidden: 64 x 512, wave w owns cols w*64..+63, acc 64 ----
        {
            f32x4 acc[4][4] = {};
            mfma_gemm<4, 4, 8>(xh, 512, 0, tW1 + (size_t)(w * 64) * 256, 256, 0, lr, lk, acc);
            store_lds<4, 4, true>(hs, 1024, 0, w * 64, b1 + w * 64, lr, lk, acc);
        }
        __syncthreads();
        // ---- f: 64 x 256, K=512; waves 2m x 4n (32 rows x 64 cols), acc 32 ----
        {
            f32x4 acc[2][4] = {};
            mfma_gemm<2, 4, 16>(hs, 1024, (w >> 2) * 32,
                                tW2 + (size_t)((w & 3) * 64) * 512, 512, 0, lr, lk, acc);
            store_lds<2, 4, false>(fs, 512, (w >> 2) * 32, (w & 3) * 64,
                                   b2 + (w & 3) * 64, lr, lk, acc);
        }
        __syncthreads();
        // ---- LN2(x+f) [+ LNf] : 8 threads/row, 32 cols each ----
        {
            int lrow = tid >> 3, c0 = (tid & 7) * 32;
            int xoff = lrow * 512, sw = (lrow & 7) << 4;
            float v[32];
            #pragma unroll
            for (int c = 0; c < 4; ++c) {
                u16x8 tx = *(const u16x8*)(xh + ((xoff + c0 * 2 + c * 16) ^ sw));
                u16x8 tf = *(const u16x8*)(fs + ((xoff + c0 * 2 + c * 16) ^ sw));
                #pragma unroll
                for (int j = 0; j < 8; ++j) v[c * 8 + j] = bf2f(tx[j]) + bf2f(tf[j]);
            }
            float s = 0.0f, sq = 0.0f;
            #pragma unroll
            for (int j = 0; j < 32; ++j) { s += v[j]; sq += v[j] * v[j]; }
            s += __shfl_xor(s, 1); s += __shfl_xor(s, 2); s += __shfl_xor(s, 4);
            sq += __shfl_xor(sq, 1); sq += __shfl_xor(sq, 2); sq += __shfl_xor(sq, 4);
            float mean = s * (1.0f / 256.0f);
            float rstd = rsqrtf(sq * (1.0f / 256.0f) - mean * mean + 1e-5f);
            if (!TAIL) {
                unsigned short* op = xout + (r0 + lrow) * 256 + c0;
                #pragma unroll
                for (int c = 0; c < 4; ++c) {
                    u16x8 t;
                    #pragma unroll
                    for (int j = 0; j < 8; ++j)
                        t[j] = f2bf((v[c * 8 + j] - mean) * rstd * g[c0 + c * 8 + j] + b[c0 + c * 8 + j]);
                    *(u16x8*)(op + c * 8) = t;
                }
            } else {
                float o[32];
                #pragma unroll
                for (int j = 0; j < 32; ++j)
                    o[j] = (v[j] - mean) * rstd * g[c0 + j] + b[c0 + j];
                float s2 = 0.0f, sq2 = 0.0f;
                #pragma unroll
                for (int j = 0; j < 32; ++j) { s2 += o[j]; sq2 += o[j] * o[j]; }
                s2 += __shfl_xor(s2, 1); s2 += __shfl_xor(s2, 2); s2 += __shfl_xor(s2, 4);
                sq2 += __shfl_xor(sq2, 1); sq2 += __shfl_xor(sq2, 2); sq2 += __shfl_xor(sq2, 4);
                float mean2 = s2 * (1.0f / 256.0f);
                float rstd2 = rsqrtf(sq2 * (1.0f / 256.0f) - mean2 * mean2 + 1e-5f);
                float* op = fout + (r0 + lrow) * 256 + c0;
                #pragma unroll
                for (int c = 0; c < 8; ++c) {
                    f32x4 t;
                    #pragma unroll
                    for (int j = 0; j < 4; ++j)
                        t[j] = (o[c * 4 + j] - mean2) * rstd2 * gf[c0 + c * 4 + j] + bf[c0 + c * 4 + j];
                    *(f32x4*)(op + c * 4) = t;
                }
            }
        }
        __syncthreads();
    }
}

// ---------------------------------------------------------------------------
// hifi: windowed 4-token attention, bf16 qkv [R][384] = [q 4h*32 | k | v].
// ---------------------------------------------------------------------------
__global__ __launch_bounds__(256) void hifi_attn(const unsigned short* __restrict__ qkv,
                                                 unsigned short* __restrict__ os)
{
    int t = blockIdx.x * 256 + threadIdx.x;
    int wdw = t >> 4, h = (t >> 2) & 3, qi = t & 3;
    int bc = wdw >> 5, tw = wdw & 31;
    int rbase = bc * 128 + (tw >> 3) * 32 + (tw & 7) * 2;
    int qrow = rbase + ((qi >> 1) << 4) + (qi & 1);

    const unsigned short* qp = qkv + (size_t)qrow * 384 + h * 32;
    float q[32];
    #pragma unroll
    for (int c = 0; c < 4; ++c) {
        u16x8 v = *(const u16x8*)(qp + c * 8);
        #pragma unroll
        for (int j = 0; j < 8; ++j) q[c * 8 + j] = bf2f(v[j]);
    }
    float s4[4];
    #pragma unroll
    for (int j = 0; j < 4; ++j) {
        int kr = rbase + ((j >> 1) << 4) + (j & 1);
        const unsigned short* kp = qkv + (size_t)kr * 384 + 128 + h * 32;
        float d = 0.0f;
        #pragma unroll
        for (int c = 0; c < 4; ++c) {
            u16x8 v = *(const u16x8*)(kp + c * 8);
            #pragma unroll
            for (int jj = 0; jj < 8; ++jj) d += q[c * 8 + jj] * bf2f(v[jj]);
        }
        s4[j] = d * ATT_SCALE;
    }
    float mx = fmaxf(fmaxf(s4[0], s4[1]), fmaxf(s4[2], s4[3]));
    float den = 0.0f;
    #pragma unroll
    for (int j = 0; j < 4; ++j) { s4[j] = __expf(s4[j] - mx); den += s4[j]; }
    float inv = 1.0f / den;

    float o[32];
    #pragma unroll
    for (int i = 0; i < 32; ++i) o[i] = 0.0f;
    #pragma unroll
    for (int j = 0; j < 4; ++j) {
        int vr = rbase + ((j >> 1) << 4) + (j & 1);
        const unsigned short* vp = qkv + (size_t)vr * 384 + 256 + h * 32;
        float a = s4[j] * inv;
        #pragma unroll
        for (int c = 0; c < 4; ++c) {
            u16x8 v = *(const u16x8*)(vp + c * 8);
            #pragma unroll
            for (int jj = 0; jj < 8; ++jj) o[c * 8 + jj] += a * bf2f(v[jj]);
        }
    }
    unsigned short* op = os + (size_t)qrow * 128 + h * 32;
    #pragma unroll
    for (int c = 0; c < 4; ++c) {
        u16x8 v;
        #pragma unroll
        for (int j = 0; j < 8; ++j) v[j] = f2bf(o[c * 8 + j]);
        *(u16x8*)(op + c * 8) = v;
    }
}

// ---------------------------------------------------------------------------
// pool: xp[p][c] = mean of the 2x2 window's 4 rows (bf16 in/out)
// ---------------------------------------------------------------------------
__global__ __launch_bounds__(256) void pool_k(const unsigned short* __restrict__ x,
                                              unsigned short* __restrict__ xp)
{
    int id = blockIdx.x * 256 + threadIdx.x;   // p*32 + chunk8
    int p = id >> 5, c8 = (id & 31) * 8;
    int bc = p >> 5, tw = p & 31;
    int rbase = bc * 128 + (tw >> 3) * 32 + (tw & 7) * 2;
    const unsigned short* x0 = x + (size_t)rbase * 256 + c8;
    float a[8] = {};
    const int offs[4] = {0, 256, 16 * 256, 17 * 256};
    #pragma unroll
    for (int r = 0; r < 4; ++r) {
        u16x8 v = *(const u16x8*)(x0 + offs[r]);
        #pragma unroll
        for (int j = 0; j < 8; ++j) a[j] += bf2f(v[j]);
    }
    u16x8 o;
    #pragma unroll
    for (int j = 0; j < 8; ++j) o[j] = f2bf(a[j] * 0.25f);
    *(u16x8*)(xp + (size_t)p * 256 + c8) = o;
}

// ---------------------------------------------------------------------------
// lofi: 128 queries vs 32 pooled kv per (bc, head).
// ---------------------------------------------------------------------------
__global__ __launch_bounds__(128) void lofi_attn(const unsigned short* __restrict__ qb,
                                                 const unsigned short* __restrict__ kvb,
                                                 unsigned short* __restrict__ ob)
{
    __shared__ float ks[32][36];
    __shared__ float vs[32][36];
    int bc = blockIdx.x >> 2, h = blockIdx.x & 3;
    int tid = threadIdx.x;

    #pragma unroll
    for (int i = 0; i < 2; ++i) {
        int fid = tid + i * 128;
        int row = fid >> 3, cc = (fid & 7) * 4;
        const unsigned short* kp = kvb + (size_t)(bc * 32 + row) * 256 + h * 32 + cc;
        u16x4 kk = *(const u16x4*)kp;
        u16x4 vv = *(const u16x4*)(kp + 128);
        #pragma unroll
        for (int j = 0; j < 4; ++j) { ks[row][cc + j] = bf2f(kk[j]); vs[row][cc + j] = bf2f(vv[j]); }
    }

    const unsigned short* qp = qb + (size_t)(bc * 128 + tid) * 128 + h * 32;
    float q[32];
    #pragma unroll
    for (int c = 0; c < 4; ++c) {
        u16x8 v = *(const u16x8*)(qp + c * 8);
        #pragma unroll
        for (int j = 0; j < 8; ++j) q[c * 8 + j] = bf2f(v[j]);
    }
    __syncthreads();

    float sc[32];
    #pragma unroll
    for (int tk = 0; tk < 32; ++tk) {
        float d = 0.0f;
        #pragma unroll
        for (int i = 0; i < 32; ++i) d += q[i] * ks[tk][i];
        sc[tk] = d * ATT_SCALE;
    }
    float mx = -1e30f;
    #pragma unroll
    for (int tk = 0; tk < 32; ++tk) mx = fmaxf(mx, sc[tk]);
    float den = 0.0f;
    #pragma unroll
    for (int tk = 0; tk < 32; ++tk) { sc[tk] = __expf(sc[tk] - mx); den += sc[tk]; }
    float inv = 1.0f / den;

    float o[32];
    #pragma unroll
    for (int i = 0; i < 32; ++i) o[i] = 0.0f;
    #pragma unroll
    for (int tk = 0; tk < 32; ++tk) {
        float a = sc[tk];
        #pragma unroll
        for (int i = 0; i < 32; ++i) o[i] += a * vs[tk][i];
    }
    unsigned short* op = ob + (size_t)(bc * 128 + tid) * 128 + h * 32;
    #pragma unroll
    for (int c = 0; c < 4; ++c) {
        u16x8 v;
        #pragma unroll
        for (int j = 0; j < 8; ++j) v[j] = f2bf(o[c * 8 + j] * inv);
        *(u16x8*)(op + c * 8) = v;
    }
}

// ---------------------------------------------------------------------------
// addln: x + [hi|lo] -> LN -> x bf16. One wave per row, lane holds 4 cols.
// ---------------------------------------------------------------------------
__global__ __launch_bounds__(256) void addln(
    const unsigned short* __restrict__ x,
    const unsigned short* __restrict__ r1,
    const unsigned short* __restrict__ r2,
    const float* __restrict__ g, const float* __restrict__ b,
    unsigned short* __restrict__ xout)
{
    size_t row = (size_t)blockIdx.x * 4 + (threadIdx.x >> 6);
    int l = threadIdx.x & 63;
    u16x4 xv = *(const u16x4*)(x + row * 256 + l * 4);
    f32x4 v;
    #pragma unroll
    for (int j = 0; j < 4; ++j) v[j] = bf2f(xv[j]);
    const unsigned short* rp = (l < 32) ? (r1 + row * 128 + l * 4)
                                        : (r2 + row * 128 + (l - 32) * 4);
    u16x4 rv = *(const u16x4*)rp;
    #pragma unroll
    for (int j = 0; j < 4; ++j) v[j] += bf2f(rv[j]);
    float s = v[0] + v[1] + v[2] + v[3];
    float sq = v[0] * v[0] + v[1] * v[1] + v[2] * v[2] + v[3] * v[3];
    #pragma unroll
    for (int off = 32; off > 0; off >>= 1) { s += __shfl_xor(s, off); sq += __shfl_xor(sq, off); }
    float mean = s * (1.0f / 256.0f);
    float rstd = rsqrtf(sq * (1.0f / 256.0f) - mean * mean + 1e-5f);
    f32x4 gv = *(const f32x4*)(g + l * 4);
    f32x4 bv = *(const f32x4*)(b + l * 4);
    u16x4 t;
    #pragma unroll
    for (int j = 0; j < 4; ++j) t[j] = f2bf((v[j] - mean) * rstd * gv[j] + bv[j]);
    *(u16x4*)(xout + row * 256 + l * 4) = t;
}

// ---------------------------------------------------------------------------
extern "C" void kernel_launch(void* const* d_in, const int* in_sizes, int n_in,
                              void* d_out, int out_size, void* d_ws, size_t ws_size,
                              hipStream_t stream)
{
    (void)in_sizes; (void)n_in; (void)out_size; (void)ws_size;
    const float* tgt   = (const float*)d_in[0];
    const float* Wlq   = (const float*)d_in[1];
    const float* Wlkv  = (const float*)d_in[2];
    const float* Wlp   = (const float*)d_in[3];
    const float* blp   = (const float*)d_in[4];
    const float* Whqkv = (const float*)d_in[5];
    const float* Whp   = (const float*)d_in[6];
    const float* bhp   = (const float*)d_in[7];
    const float* W1    = (const float*)d_in[8];
    const float* b1    = (const float*)d_in[9];
    const float* W2    = (const float*)d_in[10];
    const float* b2    = (const float*)d_in[11];
    const float* ln1g  = (const float*)d_in[12];
    const float* ln1b  = (const float*)d_in[13];
    const float* ln2g  = (const float*)d_in[14];
    const float* ln2b  = (const float*)d_in[15];
    const float* lnfg  = (const float*)d_in[16];
    const float* lnfb  = (const float*)d_in[17];

    unsigned short* wsu = (unsigned short*)d_ws;
    unsigned short* tWhqkv = wsu;             // 2*384*256
    unsigned short* tWhp   = wsu + 196608;    // 2*128*128
    unsigned short* tWlq   = wsu + 229376;    // 2*128*256
    unsigned short* tWlkv  = wsu + 294912;    // 2*256*256
    unsigned short* tWlp   = wsu + 425984;    // 2*128*128
    unsigned short* tW1    = wsu + 458752;    // 2*512*256
    unsigned short* tW2    = wsu + 720896;    // 2*256*512
    unsigned short* x    = wsu + 983040;                 // R*256
    unsigned short* qkv  = x + RT * 256;                 // R*384
    unsigned short* los  = qkv + RT * 256;               // aliases qkv tail (qkv dead)
    unsigned short* os   = qkv + RT * 384;               // R*128
    unsigned short* qb   = os;                           // aliases os
    unsigned short* xp   = os + RT * 128;                // 32768*256
    unsigned short* kv   = xp + 32768ull * 256;          // 32768*256
    unsigned short* hi   = kv + 32768ull * 256;          // R*128
    unsigned short* lo   = hi + RT * 128;                // R*128

    wprep<<<dim3(8, 12, 2), 256, 0, stream>>>(Whqkv, tWhqkv, 256, 384);
    wprep<<<dim3(4,  4, 2), 256, 0, stream>>>(Whp,   tWhp,   128, 128);
    wprep<<<dim3(8,  4, 2), 256, 0, stream>>>(Wlq,   tWlq,   256, 128);
    wprep<<<dim3(8,  8, 2), 256, 0, stream>>>(Wlkv,  tWlkv,  256, 256);
    wprep<<<dim3(4,  4, 2), 256, 0, stream>>>(Wlp,   tWlp,   128, 128);
    wprep<<<dim3(8, 16, 2), 256, 0, stream>>>(W1,    tW1,    256, 512);
    wprep<<<dim3(16, 8, 2), 256, 0, stream>>>(W2,    tW2,    512, 256);

    cvt_bf16<<<16384, 256, 0, stream>>>(tgt, x);

    hipFuncSetAttribute((const void*)ffn_fused<false>,
                        hipFuncAttributeMaxDynamicSharedMemorySize, 131072);
    hipFuncSetAttribute((const void*)ffn_fused<true>,
                        hipFuncAttributeMaxDynamicSharedMemorySize, 131072);

    for (int li = 0; li < 2; ++li) {
        // 1. qkv = x @ WhqkvT
        gemm_bb<128, false, false><<<dim3(1024, 3), 256, 0, stream>>>(
            x, 256, tWhqkv + (size_t)li * 98304, nullptr, qkv, 384, 256);
        // 2. hifi window attention -> os
        hifi_attn<<<2048, 256, 0, stream>>>(qkv, os);
        // 3. hi = os @ WhpT + bhp
        gemm_bb<128, true, false><<<dim3(1024, 1), 256, 0, stream>>>(
            os, 128, tWhp + (size_t)li * 16384, bhp + li * 128, hi, 128, 128);
        // 4. qb = x @ WlqT   (qb aliases os — os dead after step 3)
        gemm_bb<128, false, false><<<dim3(1024, 1), 256, 0, stream>>>(
            x, 256, tWlq + (size_t)li * 32768, nullptr, qb, 128, 256);
        // 5. pool
        pool_k<<<4096, 256, 0, stream>>>(x, xp);
        // 6. kv = xp @ WlkvT   (M = 32768)
        gemm_bb<128, false, false><<<dim3(256, 2), 256, 0, stream>>>(
            xp, 256, tWlkv + (size_t)li * 65536, nullptr, kv, 256, 256);
        // 7. lofi attention -> los
        lofi_attn<<<4096, 128, 0, stream>>>(qb, kv, los);
        // 8. lo = los @ WlpT + blp
        gemm_bb<128, true, false><<<dim3(1024, 1), 256, 0, stream>>>(
            los, 128, tWlp + (size_t)li * 16384, blp + li * 128, lo, 128, 128);
        // 9. x = LN(x + [hi|lo])
        addln<<<32768, 256, 0, stream>>>(x, hi, lo, ln1g + li * 256, ln1b + li * 256, x);
        // 10-12. fused FFN (+LN2, tail also LNf -> f32 out)
        if (li == 0) {
            ffn_fused<false><<<1024, 512, 131072, stream>>>(
                x, tW1, tW2, b1, b2, ln2g, ln2b, nullptr, nullptr, x, nullptr);
        } else {
            ffn_fused<true><<<1024, 512, 131072, stream>>>(
                x, tW1 + 131072, tW2 + 131072, b1 + 512, b2 + 256,
                ln2g + 256, ln2b + 256, lnfg, lnfb, nullptr, (float*)d_out);
        }
    }
}

// Round 9
// 1145.155 us; speedup vs baseline: 1.1790x; 1.1790x over previous
//
#include <hip/hip_runtime.h>
#include <hip/hip_bf16.h>

// ---------------------------------------------------------------------------
// WinEncoderTransformer, multi-kernel pipeline, bf16 activations end-to-end.
// R8 lesson (5 builds of evidence): 512-thread kernels get VGPR-pinned at 128
// and spill (R8 ffn_fused: 420MB scratch/dispatch, 445us); 256-thread kernels
// allocate sanely (gemm_bb: VGPR 56, 0 spill). So ffn_fused is rebuilt at
// 256 threads / 64 rows / 96KB LDS with per-phase live regs <= ~110:
//   stage x -> hidden (2 passes of 64 cols/wave, acc 64) -> f (acc 64,
//   stored into hs[0:32K] after drain barrier) -> fused LN2 (+LNf tail).
// Everything else kept from R8 (BN=128 GEMMs: non-FFN part measured ~460us).
// ---------------------------------------------------------------------------

#define RT 131072ull
#define ATT_SCALE 0.17677669529663687f   // 32^-0.5

typedef float f32x4 __attribute__((ext_vector_type(4)));
typedef __bf16 bf16x8 __attribute__((ext_vector_type(8)));
typedef unsigned short u16x8 __attribute__((ext_vector_type(8)));
typedef unsigned short u16x4 __attribute__((ext_vector_type(4)));

__device__ __forceinline__ unsigned short f2bf(float f) {
    unsigned int u = __float_as_uint(f);
    return (unsigned short)((u + 0x7FFFu + ((u >> 16) & 1u)) >> 16);  // RNE
}
__device__ __forceinline__ float bf2f(unsigned short s) {
    return __uint_as_float(((unsigned int)s) << 16);
}

// ---------------------------------------------------------------------------
// weight prep: src [L][K][N] f32 -> dst [L][N][K] bf16 (transposed)
// ---------------------------------------------------------------------------
__global__ __launch_bounds__(256) void wprep(const float* __restrict__ src,
                                             unsigned short* __restrict__ dst,
                                             int K, int N)
{
    __shared__ unsigned short t[32][33];
    int l = blockIdx.z;
    const float* s = src + (size_t)l * K * N;
    unsigned short* d = dst + (size_t)l * K * N;
    int r = threadIdx.x >> 3, c4 = (threadIdx.x & 7) * 4;
    int kb = blockIdx.x * 32, nb = blockIdx.y * 32;
    f32x4 v = *(const f32x4*)(s + (size_t)(kb + r) * N + nb + c4);
    #pragma unroll
    for (int j = 0; j < 4; ++j) t[c4 + j][r] = f2bf(v[j]);
    __syncthreads();
    u16x4 o;
    #pragma unroll
    for (int j = 0; j < 4; ++j) o[j] = t[r][c4 + j];
    *(u16x4*)(d + (size_t)(nb + r) * K + kb + c4) = o;
}

// ---------------------------------------------------------------------------
// cvt: tgt f32 -> x bf16
// ---------------------------------------------------------------------------
__global__ __launch_bounds__(256) void cvt_bf16(const float* __restrict__ src,
                                                unsigned short* __restrict__ dst)
{
    size_t i = ((size_t)blockIdx.x * 256 + threadIdx.x) * 8;
    f32x4 a = *(const f32x4*)(src + i);
    f32x4 b = *(const f32x4*)(src + i + 4);
    u16x8 t;
    #pragma unroll
    for (int j = 0; j < 4; ++j) { t[j] = f2bf(a[j]); t[4 + j] = f2bf(b[j]); }
    *(u16x8*)(dst + i) = t;
}

// ---------------------------------------------------------------------------
// MFMA helpers: A from swizzled LDS, B from global transposed bf16.
// Swizzle: byte = (row*stride + colbyte) ^ ((row&7)<<4)
// ---------------------------------------------------------------------------
template<int MT, int NT, int KS>
__device__ __forceinline__ void mfma_gemm(const char* As, int astride, int am0,
    const unsigned short* __restrict__ BT, int ldbk, int koff,
    int lr, int lk, f32x4 (&acc)[MT][NT])
{
    #pragma unroll
    for (int s = 0; s < KS; ++s) {
        bf16x8 bfr[NT];
        #pragma unroll
        for (int nt = 0; nt < NT; ++nt)
            bfr[nt] = *(const bf16x8*)(BT + (size_t)(nt * 16 + lr) * ldbk + koff + s * 32 + lk * 8);
        #pragma unroll
        for (int mt = 0; mt < MT; ++mt) {
            int row = am0 + mt * 16 + lr;
            bf16x8 afr = *(const bf16x8*)(As + ((row * astride + s * 64 + lk * 16) ^ ((row & 7) << 4)));
            #pragma unroll
            for (int nt = 0; nt < NT; ++nt)
                acc[mt][nt] = __builtin_amdgcn_mfma_f32_16x16x32_bf16(afr, bfr[nt], acc[mt][nt], 0, 0, 0);
        }
    }
}

template<int MT, int NT, bool RELU>
__device__ __forceinline__ void store_lds(char* Ds, int dstride, int dm0, int dn0,
    const float* bias, int lr, int lk, f32x4 (&acc)[MT][NT])
{
    #pragma unroll
    for (int nt = 0; nt < NT; ++nt) {
        float bv = bias ? bias[nt * 16 + lr] : 0.0f;
        #pragma unroll
        for (int mt = 0; mt < MT; ++mt) {
            #pragma unroll
            for (int j = 0; j < 4; ++j) {
                int row = dm0 + mt * 16 + lk * 4 + j;
                int col = dn0 + nt * 16 + lr;
                float v = acc[mt][nt][j] + bv;
                if (RELU) v = fmaxf(v, 0.0f);
                *(unsigned short*)(Ds + ((row * dstride + col * 2) ^ ((row & 7) << 4))) = f2bf(v);
            }
        }
    }
}

// ---------------------------------------------------------------------------
// GEMM: C[M x N] = A[M x K] @ BT[N x K]^T (+bias)(+relu), bf16 in/out, MFMA.
// BM=128, BN templated, BK=64, 256 threads (2x2 waves).
// ---------------------------------------------------------------------------
template<int BN, bool BIAS, bool RELU>
__global__ __launch_bounds__(256) void gemm_bb(
    const unsigned short* __restrict__ A, int lda,
    const unsigned short* __restrict__ BT,
    const float* __restrict__ bias,
    unsigned short* __restrict__ C, int ldc, int K)
{
    constexpr int NT = BN / 32;
    __shared__ __align__(16) char As[128 * 128];
    __shared__ __align__(16) char Bs[BN * 128];

    const int tid = threadIdx.x;
    const size_t m0 = (size_t)blockIdx.x * 128;
    const int n0 = blockIdx.y * BN;
    const int w = tid >> 6, l = tid & 63;
    const int lr = l & 15, lk = l >> 4;
    const int wm = w >> 1, wn = w & 1;

    f32x4 acc[4][NT] = {};

    for (int k0 = 0; k0 < K; k0 += 64) {
        #pragma unroll
        for (int i = 0; i < 4; ++i) {
            int cid = tid + i * 256, row = cid >> 3, kc = cid & 7;
            u16x8 t = *(const u16x8*)(A + (m0 + row) * lda + k0 + kc * 8);
            *(u16x8*)(As + ((row * 128 + kc * 16) ^ ((row & 7) << 4))) = t;
        }
        #pragma unroll
        for (int i = 0; i < BN / 32; ++i) {
            int fid = tid + i * 256, row = fid >> 3, kc = fid & 7;
            u16x8 t = *(const u16x8*)(BT + (size_t)(n0 + row) * K + k0 + kc * 8);
            *(u16x8*)(Bs + ((row * 128 + kc * 16) ^ ((row & 7) << 4))) = t;
        }
        __syncthreads();
        #pragma unroll
        for (int s = 0; s < 2; ++s) {
            bf16x8 bfr[NT];
            #pragma unroll
            for (int nt = 0; nt < NT; ++nt) {
                int r = wn * (BN / 2) + nt * 16 + lr;
                bfr[nt] = *(const bf16x8*)(Bs + ((r * 128 + s * 64 + lk * 16) ^ ((r & 7) << 4)));
            }
            #pragma unroll
            for (int mt = 0; mt < 4; ++mt) {
                int r = wm * 64 + mt * 16 + lr;
                bf16x8 afr = *(const bf16x8*)(As + ((r * 128 + s * 64 + lk * 16) ^ ((r & 7) << 4)));
                #pragma unroll
                for (int nt = 0; nt < NT; ++nt)
                    acc[mt][nt] = __builtin_amdgcn_mfma_f32_16x16x32_bf16(afr, bfr[nt], acc[mt][nt], 0, 0, 0);
            }
        }
        __syncthreads();
    }
    #pragma unroll
    for (int nt = 0; nt < NT; ++nt) {
        int col = n0 + wn * (BN / 2) + nt * 16 + lr;
        float bv = BIAS ? bias[col] : 0.0f;
        #pragma unroll
        for (int mt = 0; mt < 4; ++mt) {
            #pragma unroll
            for (int j = 0; j < 4; ++j) {
                size_t row = m0 + (size_t)(wm * 64 + mt * 16 + lk * 4 + j);
                float v = acc[mt][nt][j] + bv;
                if (RELU) v = fmaxf(v, 0.0f);
                C[row * ldc + col] = f2bf(v);
            }
        }
    }
}

// ---------------------------------------------------------------------------
// Fused FFN, 256 threads (4 waves), 64 rows/block, grid 2048.
// LDS 96KB dyn: xh[64][256]bf16 (32K, swz) | hs[64][512]bf16 (64K, swz).
// Phases: stage x -> hidden (2 passes: wave w cols p*256+w*64, acc 64)
//   -> f (wave w cols w*64, K=512, acc 64; after drain barrier stored to
//      hs[0:32K] as [64][256] stride 512) -> LN2(x+f) [-> LNf -> f32 out].
// ---------------------------------------------------------------------------
template<bool TAIL>
__global__ __launch_bounds__(256) void ffn_fused(
    const unsigned short* __restrict__ x,
    const unsigned short* __restrict__ tW1,   // [512][256] this layer
    const unsigned short* __restrict__ tW2,   // [256][512] this layer
    const float* __restrict__ b1, const float* __restrict__ b2,
    const float* __restrict__ g, const float* __restrict__ b,     // ln2
    const float* __restrict__ gf, const float* __restrict__ bf,   // final ln
    unsigned short* __restrict__ xout, float* __restrict__ fout)
{
    extern __shared__ char smem[];
    char* xh = smem;            // [64][256] bf16, stride 512, swizzled
    char* hs = smem + 32768;    // [64][512] bf16, stride 1024, swizzled

    const int tid = threadIdx.x;
    const int w = tid >> 6, l = tid & 63;
    const int lr = l & 15, lk = l >> 4;
    const size_t r0 = (size_t)blockIdx.x * 64;

    // ---- stage x: 64 x 256 bf16 = 2048 16B chunks, 8/thread ----
    #pragma unroll
    for (int i = 0; i < 8; ++i) {
        int cid = tid + i * 256;
        int row = cid >> 5, c8 = (cid & 31) * 8;
        u16x8 t = *(const u16x8*)(x + (r0 + row) * 256 + c8);
        *(u16x8*)(xh + ((row * 512 + c8 * 2) ^ ((row & 7) << 4))) = t;
    }
    __syncthreads();
    // ---- hidden: 64 x 512 = two passes of 64 cols per wave (acc 64) ----
    #pragma unroll
    for (int p = 0; p < 2; ++p) {
        f32x4 acc[4][4] = {};
        mfma_gemm<4, 4, 8>(xh, 512, 0,
            tW1 + (size_t)(p * 256 + w * 64) * 256, 256, 0, lr, lk, acc);
        store_lds<4, 4, true>(hs, 1024, 0, p * 256 + w * 64,
                              b1 + p * 256 + w * 64, lr, lk, acc);
        __syncthreads();
    }
    // ---- f: 64 x 256, K=512, wave w cols w*64 (acc 64) ----
    {
        f32x4 acc[4][4] = {};
        mfma_gemm<4, 4, 16>(hs, 1024, 0,
            tW2 + (size_t)(w * 64) * 512, 512, 0, lr, lk, acc);
        __syncthreads();   // drain all hs reads before overwriting hs[0:32K]
        store_lds<4, 4, false>(hs, 512, 0, w * 64, b2 + w * 64, lr, lk, acc);
    }
    __syncthreads();
    // ---- LN2(x+f) [+ LNf] : 4 threads/row, 64 cols each ----
    {
        int lrow = tid >> 2, c0 = (tid & 3) * 64;
        int xo = lrow * 512, sw = (lrow & 7) << 4;
        float v[64];
        #pragma unroll
        for (int c = 0; c < 8; ++c) {
            u16x8 tx = *(const u16x8*)(xh + ((xo + c0 * 2 + c * 16) ^ sw));
            u16x8 tf = *(const u16x8*)(hs + ((xo + c0 * 2 + c * 16) ^ sw));
            #pragma unroll
            for (int j = 0; j < 8; ++j) v[c * 8 + j] = bf2f(tx[j]) + bf2f(tf[j]);
        }
        float s = 0.0f, sq = 0.0f;
        #pragma unroll
        for (int j = 0; j < 64; ++j) { s += v[j]; sq += v[j] * v[j]; }
        s += __shfl_xor(s, 1); s += __shfl_xor(s, 2);
        sq += __shfl_xor(sq, 1); sq += __shfl_xor(sq, 2);
        float mean = s * (1.0f / 256.0f);
        float rstd = rsqrtf(sq * (1.0f / 256.0f) - mean * mean + 1e-5f);
        if (!TAIL) {
            unsigned short* op = xout + (r0 + lrow) * 256 + c0;
            #pragma unroll
            for (int c = 0; c < 8; ++c) {
                u16x8 t;
                #pragma unroll
                for (int j = 0; j < 8; ++j)
                    t[j] = f2bf((v[c * 8 + j] - mean) * rstd * g[c0 + c * 8 + j] + b[c0 + c * 8 + j]);
                *(u16x8*)(op + c * 8) = t;
            }
        } else {
            float s2 = 0.0f, sq2 = 0.0f;
            #pragma unroll
            for (int j = 0; j < 64; ++j) {
                float o = (v[j] - mean) * rstd * g[c0 + j] + b[c0 + j];
                s2 += o; sq2 += o * o;
            }
            s2 += __shfl_xor(s2, 1); s2 += __shfl_xor(s2, 2);
            sq2 += __shfl_xor(sq2, 1); sq2 += __shfl_xor(sq2, 2);
            float mean2 = s2 * (1.0f / 256.0f);
            float rstd2 = rsqrtf(sq2 * (1.0f / 256.0f) - mean2 * mean2 + 1e-5f);
            float* op = fout + (r0 + lrow) * 256 + c0;
            #pragma unroll
            for (int c = 0; c < 16; ++c) {
                f32x4 t;
                #pragma unroll
                for (int j = 0; j < 4; ++j) {
                    float o = (v[c * 4 + j] - mean) * rstd * g[c0 + c * 4 + j] + b[c0 + c * 4 + j];
                    t[j] = (o - mean2) * rstd2 * gf[c0 + c * 4 + j] + bf[c0 + c * 4 + j];
                }
                *(f32x4*)(op + c * 4) = t;
            }
        }
    }
}

// ---------------------------------------------------------------------------
// hifi: windowed 4-token attention, bf16 qkv [R][384] = [q 4h*32 | k | v].
// ---------------------------------------------------------------------------
__global__ __launch_bounds__(256) void hifi_attn(const unsigned short* __restrict__ qkv,
                                                 unsigned short* __restrict__ os)
{
    int t = blockIdx.x * 256 + threadIdx.x;
    int wdw = t >> 4, h = (t >> 2) & 3, qi = t & 3;
    int bc = wdw >> 5, tw = wdw & 31;
    int rbase = bc * 128 + (tw >> 3) * 32 + (tw & 7) * 2;
    int qrow = rbase + ((qi >> 1) << 4) + (qi & 1);

    const unsigned short* qp = qkv + (size_t)qrow * 384 + h * 32;
    float q[32];
    #pragma unroll
    for (int c = 0; c < 4; ++c) {
        u16x8 v = *(const u16x8*)(qp + c * 8);
        #pragma unroll
        for (int j = 0; j < 8; ++j) q[c * 8 + j] = bf2f(v[j]);
    }
    float s4[4];
    #pragma unroll
    for (int j = 0; j < 4; ++j) {
        int kr = rbase + ((j >> 1) << 4) + (j & 1);
        const unsigned short* kp = qkv + (size_t)kr * 384 + 128 + h * 32;
        float d = 0.0f;
        #pragma unroll
        for (int c = 0; c < 4; ++c) {
            u16x8 v = *(const u16x8*)(kp + c * 8);
            #pragma unroll
            for (int jj = 0; jj < 8; ++jj) d += q[c * 8 + jj] * bf2f(v[jj]);
        }
        s4[j] = d * ATT_SCALE;
    }
    float mx = fmaxf(fmaxf(s4[0], s4[1]), fmaxf(s4[2], s4[3]));
    float den = 0.0f;
    #pragma unroll
    for (int j = 0; j < 4; ++j) { s4[j] = __expf(s4[j] - mx); den += s4[j]; }
    float inv = 1.0f / den;

    float o[32];
    #pragma unroll
    for (int i = 0; i < 32; ++i) o[i] = 0.0f;
    #pragma unroll
    for (int j = 0; j < 4; ++j) {
        int vr = rbase + ((j >> 1) << 4) + (j & 1);
        const unsigned short* vp = qkv + (size_t)vr * 384 + 256 + h * 32;
        float a = s4[j] * inv;
        #pragma unroll
        for (int c = 0; c < 4; ++c) {
            u16x8 v = *(const u16x8*)(vp + c * 8);
            #pragma unroll
            for (int jj = 0; jj < 8; ++jj) o[c * 8 + jj] += a * bf2f(v[jj]);
        }
    }
    unsigned short* op = os + (size_t)qrow * 128 + h * 32;
    #pragma unroll
    for (int c = 0; c < 4; ++c) {
        u16x8 v;
        #pragma unroll
        for (int j = 0; j < 8; ++j) v[j] = f2bf(o[c * 8 + j]);
        *(u16x8*)(op + c * 8) = v;
    }
}

// ---------------------------------------------------------------------------
// pool: xp[p][c] = mean of the 2x2 window's 4 rows (bf16 in/out)
// ---------------------------------------------------------------------------
__global__ __launch_bounds__(256) void pool_k(const unsigned short* __restrict__ x,
                                              unsigned short* __restrict__ xp)
{
    int id = blockIdx.x * 256 + threadIdx.x;
    int p = id >> 5, c8 = (id & 31) * 8;
    int bc = p >> 5, tw = p & 31;
    int rbase = bc * 128 + (tw >> 3) * 32 + (tw & 7) * 2;
    const unsigned short* x0 = x + (size_t)rbase * 256 + c8;
    float a[8] = {};
    const int offs[4] = {0, 256, 16 * 256, 17 * 256};
    #pragma unroll
    for (int r = 0; r < 4; ++r) {
        u16x8 v = *(const u16x8*)(x0 + offs[r]);
        #pragma unroll
        for (int j = 0; j < 8; ++j) a[j] += bf2f(v[j]);
    }
    u16x8 o;
    #pragma unroll
    for (int j = 0; j < 8; ++j) o[j] = f2bf(a[j] * 0.25f);
    *(u16x8*)(xp + (size_t)p * 256 + c8) = o;
}

// ---------------------------------------------------------------------------
// lofi: 128 queries vs 32 pooled kv per (bc, head).
// ---------------------------------------------------------------------------
__global__ __launch_bounds__(128) void lofi_attn(const unsigned short* __restrict__ qb,
                                                 const unsigned short* __restrict__ kvb,
                                                 unsigned short* __restrict__ ob)
{
    __shared__ float ks[32][36];
    __shared__ float vs[32][36];
    int bc = blockIdx.x >> 2, h = blockIdx.x & 3;
    int tid = threadIdx.x;

    #pragma unroll
    for (int i = 0; i < 2; ++i) {
        int fid = tid + i * 128;
        int row = fid >> 3, cc = (fid & 7) * 4;
        const unsigned short* kp = kvb + (size_t)(bc * 32 + row) * 256 + h * 32 + cc;
        u16x4 kk = *(const u16x4*)kp;
        u16x4 vv = *(const u16x4*)(kp + 128);
        #pragma unroll
        for (int j = 0; j < 4; ++j) { ks[row][cc + j] = bf2f(kk[j]); vs[row][cc + j] = bf2f(vv[j]); }
    }

    const unsigned short* qp = qb + (size_t)(bc * 128 + tid) * 128 + h * 32;
    float q[32];
    #pragma unroll
    for (int c = 0; c < 4; ++c) {
        u16x8 v = *(const u16x8*)(qp + c * 8);
        #pragma unroll
        for (int j = 0; j < 8; ++j) q[c * 8 + j] = bf2f(v[j]);
    }
    __syncthreads();

    float sc[32];
    #pragma unroll
    for (int tk = 0; tk < 32; ++tk) {
        float d = 0.0f;
        #pragma unroll
        for (int i = 0; i < 32; ++i) d += q[i] * ks[tk][i];
        sc[tk] = d * ATT_SCALE;
    }
    float mx = -1e30f;
    #pragma unroll
    for (int tk = 0; tk < 32; ++tk) mx = fmaxf(mx, sc[tk]);
    float den = 0.0f;
    #pragma unroll
    for (int tk = 0; tk < 32; ++tk) { sc[tk] = __expf(sc[tk] - mx); den += sc[tk]; }
    float inv = 1.0f / den;

    float o[32];
    #pragma unroll
    for (int i = 0; i < 32; ++i) o[i] = 0.0f;
    #pragma unroll
    for (int tk = 0; tk < 32; ++tk) {
        float a = sc[tk];
        #pragma unroll
        for (int i = 0; i < 32; ++i) o[i] += a * vs[tk][i];
    }
    unsigned short* op = ob + (size_t)(bc * 128 + tid) * 128 + h * 32;
    #pragma unroll
    for (int c = 0; c < 4; ++c) {
        u16x8 v;
        #pragma unroll
        for (int j = 0; j < 8; ++j) v[j] = f2bf(o[c * 8 + j] * inv);
        *(u16x8*)(op + c * 8) = v;
    }
}

// ---------------------------------------------------------------------------
// addln: x + [hi|lo] -> LN -> x bf16. One wave per row, lane holds 4 cols.
// ---------------------------------------------------------------------------
__global__ __launch_bounds__(256) void addln(
    const unsigned short* __restrict__ x,
    const unsigned short* __restrict__ r1,
    const unsigned short* __restrict__ r2,
    const float* __restrict__ g, const float* __restrict__ b,
    unsigned short* __restrict__ xout)
{
    size_t row = (size_t)blockIdx.x * 4 + (threadIdx.x >> 6);
    int l = threadIdx.x & 63;
    u16x4 xv = *(const u16x4*)(x + row * 256 + l * 4);
    f32x4 v;
    #pragma unroll
    for (int j = 0; j < 4; ++j) v[j] = bf2f(xv[j]);
    const unsigned short* rp = (l < 32) ? (r1 + row * 128 + l * 4)
                                        : (r2 + row * 128 + (l - 32) * 4);
    u16x4 rv = *(const u16x4*)rp;
    #pragma unroll
    for (int j = 0; j < 4; ++j) v[j] += bf2f(rv[j]);
    float s = v[0] + v[1] + v[2] + v[3];
    float sq = v[0] * v[0] + v[1] * v[1] + v[2] * v[2] + v[3] * v[3];
    #pragma unroll
    for (int off = 32; off > 0; off >>= 1) { s += __shfl_xor(s, off); sq += __shfl_xor(sq, off); }
    float mean = s * (1.0f / 256.0f);
    float rstd = rsqrtf(sq * (1.0f / 256.0f) - mean * mean + 1e-5f);
    f32x4 gv = *(const f32x4*)(g + l * 4);
    f32x4 bv = *(const f32x4*)(b + l * 4);
    u16x4 t;
    #pragma unroll
    for (int j = 0; j < 4; ++j) t[j] = f2bf((v[j] - mean) * rstd * gv[j] + bv[j]);
    *(u16x4*)(xout + row * 256 + l * 4) = t;
}

// ---------------------------------------------------------------------------
extern "C" void kernel_launch(void* const* d_in, const int* in_sizes, int n_in,
                              void* d_out, int out_size, void* d_ws, size_t ws_size,
                              hipStream_t stream)
{
    (void)in_sizes; (void)n_in; (void)out_size; (void)ws_size;
    const float* tgt   = (const float*)d_in[0];
    const float* Wlq   = (const float*)d_in[1];
    const float* Wlkv  = (const float*)d_in[2];
    const float* Wlp   = (const float*)d_in[3];
    const float* blp   = (const float*)d_in[4];
    const float* Whqkv = (const float*)d_in[5];
    const float* Whp   = (const float*)d_in[6];
    const float* bhp   = (const float*)d_in[7];
    const float* W1    = (const float*)d_in[8];
    const float* b1    = (const float*)d_in[9];
    const float* W2    = (const float*)d_in[10];
    const float* b2    = (const float*)d_in[11];
    const float* ln1g  = (const float*)d_in[12];
    const float* ln1b  = (const float*)d_in[13];
    const float* ln2g  = (const float*)d_in[14];
    const float* ln2b  = (const float*)d_in[15];
    const float* lnfg  = (const float*)d_in[16];
    const float* lnfb  = (const float*)d_in[17];

    unsigned short* wsu = (unsigned short*)d_ws;
    unsigned short* tWhqkv = wsu;             // 2*384*256
    unsigned short* tWhp   = wsu + 196608;    // 2*128*128
    unsigned short* tWlq   = wsu + 229376;    // 2*128*256
    unsigned short* tWlkv  = wsu + 294912;    // 2*256*256
    unsigned short* tWlp   = wsu + 425984;    // 2*128*128
    unsigned short* tW1    = wsu + 458752;    // 2*512*256
    unsigned short* tW2    = wsu + 720896;    // 2*256*512
    unsigned short* x    = wsu + 983040;                 // R*256
    unsigned short* qkv  = x + RT * 256;                 // R*384
    unsigned short* los  = qkv + RT * 256;               // aliases qkv tail
    unsigned short* os   = qkv + RT * 384;               // R*128
    unsigned short* qb   = os;                           // aliases os
    unsigned short* xp   = os + RT * 128;                // 32768*256
    unsigned short* kv   = xp + 32768ull * 256;          // 32768*256
    unsigned short* hi   = kv + 32768ull * 256;          // R*128
    unsigned short* lo   = hi + RT * 128;                // R*128

    wprep<<<dim3(8, 12, 2), 256, 0, stream>>>(Whqkv, tWhqkv, 256, 384);
    wprep<<<dim3(4,  4, 2), 256, 0, stream>>>(Whp,   tWhp,   128, 128);
    wprep<<<dim3(8,  4, 2), 256, 0, stream>>>(Wlq,   tWlq,   256, 128);
    wprep<<<dim3(8,  8, 2), 256, 0, stream>>>(Wlkv,  tWlkv,  256, 256);
    wprep<<<dim3(4,  4, 2), 256, 0, stream>>>(Wlp,   tWlp,   128, 128);
    wprep<<<dim3(8, 16, 2), 256, 0, stream>>>(W1,    tW1,    256, 512);
    wprep<<<dim3(16, 8, 2), 256, 0, stream>>>(W2,    tW2,    512, 256);

    cvt_bf16<<<16384, 256, 0, stream>>>(tgt, x);

    hipFuncSetAttribute((const void*)ffn_fused<false>,
                        hipFuncAttributeMaxDynamicSharedMemorySize, 98304);
    hipFuncSetAttribute((const void*)ffn_fused<true>,
                        hipFuncAttributeMaxDynamicSharedMemorySize, 98304);

    for (int li = 0; li < 2; ++li) {
        // 1. qkv = x @ WhqkvT
        gemm_bb<128, false, false><<<dim3(1024, 3), 256, 0, stream>>>(
            x, 256, tWhqkv + (size_t)li * 98304, nullptr, qkv, 384, 256);
        // 2. hifi window attention -> os
        hifi_attn<<<2048, 256, 0, stream>>>(qkv, os);
        // 3. hi = os @ WhpT + bhp
        gemm_bb<128, true, false><<<dim3(1024, 1), 256, 0, stream>>>(
            os, 128, tWhp + (size_t)li * 16384, bhp + li * 128, hi, 128, 128);
        // 4. qb = x @ WlqT   (qb aliases os — os dead after step 3)
        gemm_bb<128, false, false><<<dim3(1024, 1), 256, 0, stream>>>(
            x, 256, tWlq + (size_t)li * 32768, nullptr, qb, 128, 256);
        // 5. pool
        pool_k<<<4096, 256, 0, stream>>>(x, xp);
        // 6. kv = xp @ WlkvT   (M = 32768)
        gemm_bb<128, false, false><<<dim3(256, 2), 256, 0, stream>>>(
            xp, 256, tWlkv + (size_t)li * 65536, nullptr, kv, 256, 256);
        // 7. lofi attention -> los
        lofi_attn<<<4096, 128, 0, stream>>>(qb, kv, los);
        // 8. lo = los @ WlpT + blp
        gemm_bb<128, true, false><<<dim3(1024, 1), 256, 0, stream>>>(
            los, 128, tWlp + (size_t)li * 16384, blp + li * 128, lo, 128, 128);
        // 9. x = LN(x + [hi|lo])
        addln<<<32768, 256, 0, stream>>>(x, hi, lo, ln1g + li * 256, ln1b + li * 256, x);
        // 10-12. fused FFN (+LN2, tail also LNf -> f32 out)
        if (li == 0) {
            ffn_fused<false><<<2048, 256, 98304, stream>>>(
                x, tW1, tW2, b1, b2, ln2g, ln2b, nullptr, nullptr, x, nullptr);
        } else {
            ffn_fused<true><<<2048, 256, 98304, stream>>>(
                x, tW1 + 131072, tW2 + 131072, b1 + 512, b2 + 256,
                ln2g + 256, ln2b + 256, lnfg, lnfb, nullptr, (float*)d_out);
        }
    }
}

// Round 10
// 953.217 us; speedup vs baseline: 1.4164x; 1.2014x over previous
//
#include <hip/hip_runtime.h>
#include <hip/hip_bf16.h>

// ---------------------------------------------------------------------------
// WinEncoderTransformer, multi-kernel pipeline, bf16 activations end-to-end.
// R9 lesson: both FFN-fusion attempts failed structurally (512-thr: VGPR pin
// + spill; 256-thr/96KB: 1 block/CU -> 1 wave/SIMD latency starvation).
// FFN is now composed from measured-known-good parts: gemm_bb (256thr, 24KB
// LDS, 4.1 TB/s traffic-bound) for h and f, addln<1>/<2> for residual+LN2
// (tail fuses final LN -> f32 out, proven in R7). Non-FFN part kept (365us
// measured in R9 with BN=128).
// ---------------------------------------------------------------------------

#define RT 131072ull
#define ATT_SCALE 0.17677669529663687f   // 32^-0.5

typedef float f32x4 __attribute__((ext_vector_type(4)));
typedef __bf16 bf16x8 __attribute__((ext_vector_type(8)));
typedef unsigned short u16x8 __attribute__((ext_vector_type(8)));
typedef unsigned short u16x4 __attribute__((ext_vector_type(4)));

__device__ __forceinline__ unsigned short f2bf(float f) {
    unsigned int u = __float_as_uint(f);
    return (unsigned short)((u + 0x7FFFu + ((u >> 16) & 1u)) >> 16);  // RNE
}
__device__ __forceinline__ float bf2f(unsigned short s) {
    return __uint_as_float(((unsigned int)s) << 16);
}

// ---------------------------------------------------------------------------
// weight prep: src [L][K][N] f32 -> dst [L][N][K] bf16 (transposed)
// ---------------------------------------------------------------------------
__global__ __launch_bounds__(256) void wprep(const float* __restrict__ src,
                                             unsigned short* __restrict__ dst,
                                             int K, int N)
{
    __shared__ unsigned short t[32][33];
    int l = blockIdx.z;
    const float* s = src + (size_t)l * K * N;
    unsigned short* d = dst + (size_t)l * K * N;
    int r = threadIdx.x >> 3, c4 = (threadIdx.x & 7) * 4;
    int kb = blockIdx.x * 32, nb = blockIdx.y * 32;
    f32x4 v = *(const f32x4*)(s + (size_t)(kb + r) * N + nb + c4);
    #pragma unroll
    for (int j = 0; j < 4; ++j) t[c4 + j][r] = f2bf(v[j]);
    __syncthreads();
    u16x4 o;
    #pragma unroll
    for (int j = 0; j < 4; ++j) o[j] = t[r][c4 + j];
    *(u16x4*)(d + (size_t)(nb + r) * K + kb + c4) = o;
}

// ---------------------------------------------------------------------------
// cvt: tgt f32 -> x bf16
// ---------------------------------------------------------------------------
__global__ __launch_bounds__(256) void cvt_bf16(const float* __restrict__ src,
                                                unsigned short* __restrict__ dst)
{
    size_t i = ((size_t)blockIdx.x * 256 + threadIdx.x) * 8;
    f32x4 a = *(const f32x4*)(src + i);
    f32x4 b = *(const f32x4*)(src + i + 4);
    u16x8 t;
    #pragma unroll
    for (int j = 0; j < 4; ++j) { t[j] = f2bf(a[j]); t[4 + j] = f2bf(b[j]); }
    *(u16x8*)(dst + i) = t;
}

// ---------------------------------------------------------------------------
// GEMM: C[M x N] = A[M x K] @ BT[N x K]^T (+bias)(+relu), bf16 in/out, MFMA.
// BM=128, BN templated, BK=64, 256 threads (2x2 waves). XOR-swizzled LDS.
// Measured (R7/R9): VGPR 56, 0 bank conflicts, ~4.1 TB/s traffic-bound.
// ---------------------------------------------------------------------------
template<int BN, bool BIAS, bool RELU>
__global__ __launch_bounds__(256) void gemm_bb(
    const unsigned short* __restrict__ A, int lda,
    const unsigned short* __restrict__ BT,
    const float* __restrict__ bias,
    unsigned short* __restrict__ C, int ldc, int K)
{
    constexpr int NT = BN / 32;
    __shared__ __align__(16) char As[128 * 128];
    __shared__ __align__(16) char Bs[BN * 128];

    const int tid = threadIdx.x;
    const size_t m0 = (size_t)blockIdx.x * 128;
    const int n0 = blockIdx.y * BN;
    const int w = tid >> 6, l = tid & 63;
    const int lr = l & 15, lk = l >> 4;
    const int wm = w >> 1, wn = w & 1;

    f32x4 acc[4][NT] = {};

    for (int k0 = 0; k0 < K; k0 += 64) {
        #pragma unroll
        for (int i = 0; i < 4; ++i) {
            int cid = tid + i * 256, row = cid >> 3, kc = cid & 7;
            u16x8 t = *(const u16x8*)(A + (m0 + row) * lda + k0 + kc * 8);
            *(u16x8*)(As + ((row * 128 + kc * 16) ^ ((row & 7) << 4))) = t;
        }
        #pragma unroll
        for (int i = 0; i < BN / 32; ++i) {
            int fid = tid + i * 256, row = fid >> 3, kc = fid & 7;
            u16x8 t = *(const u16x8*)(BT + (size_t)(n0 + row) * K + k0 + kc * 8);
            *(u16x8*)(Bs + ((row * 128 + kc * 16) ^ ((row & 7) << 4))) = t;
        }
        __syncthreads();
        #pragma unroll
        for (int s = 0; s < 2; ++s) {
            bf16x8 bfr[NT];
            #pragma unroll
            for (int nt = 0; nt < NT; ++nt) {
                int r = wn * (BN / 2) + nt * 16 + lr;
                bfr[nt] = *(const bf16x8*)(Bs + ((r * 128 + s * 64 + lk * 16) ^ ((r & 7) << 4)));
            }
            #pragma unroll
            for (int mt = 0; mt < 4; ++mt) {
                int r = wm * 64 + mt * 16 + lr;
                bf16x8 afr = *(const bf16x8*)(As + ((r * 128 + s * 64 + lk * 16) ^ ((r & 7) << 4)));
                #pragma unroll
                for (int nt = 0; nt < NT; ++nt)
                    acc[mt][nt] = __builtin_amdgcn_mfma_f32_16x16x32_bf16(afr, bfr[nt], acc[mt][nt], 0, 0, 0);
            }
        }
        __syncthreads();
    }
    #pragma unroll
    for (int nt = 0; nt < NT; ++nt) {
        int col = n0 + wn * (BN / 2) + nt * 16 + lr;
        float bv = BIAS ? bias[col] : 0.0f;
        #pragma unroll
        for (int mt = 0; mt < 4; ++mt) {
            #pragma unroll
            for (int j = 0; j < 4; ++j) {
                size_t row = m0 + (size_t)(wm * 64 + mt * 16 + lk * 4 + j);
                float v = acc[mt][nt][j] + bv;
                if (RELU) v = fmaxf(v, 0.0f);
                C[row * ldc + col] = f2bf(v);
            }
        }
    }
}

// ---------------------------------------------------------------------------
// hifi: windowed 4-token attention, bf16 qkv [R][384] = [q 4h*32 | k | v].
// ---------------------------------------------------------------------------
__global__ __launch_bounds__(256) void hifi_attn(const unsigned short* __restrict__ qkv,
                                                 unsigned short* __restrict__ os)
{
    int t = blockIdx.x * 256 + threadIdx.x;
    int wdw = t >> 4, h = (t >> 2) & 3, qi = t & 3;
    int bc = wdw >> 5, tw = wdw & 31;
    int rbase = bc * 128 + (tw >> 3) * 32 + (tw & 7) * 2;
    int qrow = rbase + ((qi >> 1) << 4) + (qi & 1);

    const unsigned short* qp = qkv + (size_t)qrow * 384 + h * 32;
    float q[32];
    #pragma unroll
    for (int c = 0; c < 4; ++c) {
        u16x8 v = *(const u16x8*)(qp + c * 8);
        #pragma unroll
        for (int j = 0; j < 8; ++j) q[c * 8 + j] = bf2f(v[j]);
    }
    float s4[4];
    #pragma unroll
    for (int j = 0; j < 4; ++j) {
        int kr = rbase + ((j >> 1) << 4) + (j & 1);
        const unsigned short* kp = qkv + (size_t)kr * 384 + 128 + h * 32;
        float d = 0.0f;
        #pragma unroll
        for (int c = 0; c < 4; ++c) {
            u16x8 v = *(const u16x8*)(kp + c * 8);
            #pragma unroll
            for (int jj = 0; jj < 8; ++jj) d += q[c * 8 + jj] * bf2f(v[jj]);
        }
        s4[j] = d * ATT_SCALE;
    }
    float mx = fmaxf(fmaxf(s4[0], s4[1]), fmaxf(s4[2], s4[3]));
    float den = 0.0f;
    #pragma unroll
    for (int j = 0; j < 4; ++j) { s4[j] = __expf(s4[j] - mx); den += s4[j]; }
    float inv = 1.0f / den;

    float o[32];
    #pragma unroll
    for (int i = 0; i < 32; ++i) o[i] = 0.0f;
    #pragma unroll
    for (int j = 0; j < 4; ++j) {
        int vr = rbase + ((j >> 1) << 4) + (j & 1);
        const unsigned short* vp = qkv + (size_t)vr * 384 + 256 + h * 32;
        float a = s4[j] * inv;
        #pragma unroll
        for (int c = 0; c < 4; ++c) {
            u16x8 v = *(const u16x8*)(vp + c * 8);
            #pragma unroll
            for (int jj = 0; jj < 8; ++jj) o[c * 8 + jj] += a * bf2f(v[jj]);
        }
    }
    unsigned short* op = os + (size_t)qrow * 128 + h * 32;
    #pragma unroll
    for (int c = 0; c < 4; ++c) {
        u16x8 v;
        #pragma unroll
        for (int j = 0; j < 8; ++j) v[j] = f2bf(o[c * 8 + j]);
        *(u16x8*)(op + c * 8) = v;
    }
}

// ---------------------------------------------------------------------------
// pool: xp[p][c] = mean of the 2x2 window's 4 rows (bf16 in/out)
// ---------------------------------------------------------------------------
__global__ __launch_bounds__(256) void pool_k(const unsigned short* __restrict__ x,
                                              unsigned short* __restrict__ xp)
{
    int id = blockIdx.x * 256 + threadIdx.x;
    int p = id >> 5, c8 = (id & 31) * 8;
    int bc = p >> 5, tw = p & 31;
    int rbase = bc * 128 + (tw >> 3) * 32 + (tw & 7) * 2;
    const unsigned short* x0 = x + (size_t)rbase * 256 + c8;
    float a[8] = {};
    const int offs[4] = {0, 256, 16 * 256, 17 * 256};
    #pragma unroll
    for (int r = 0; r < 4; ++r) {
        u16x8 v = *(const u16x8*)(x0 + offs[r]);
        #pragma unroll
        for (int j = 0; j < 8; ++j) a[j] += bf2f(v[j]);
    }
    u16x8 o;
    #pragma unroll
    for (int j = 0; j < 8; ++j) o[j] = f2bf(a[j] * 0.25f);
    *(u16x8*)(xp + (size_t)p * 256 + c8) = o;
}

// ---------------------------------------------------------------------------
// lofi: 128 queries vs 32 pooled kv per (bc, head).
// ---------------------------------------------------------------------------
__global__ __launch_bounds__(128) void lofi_attn(const unsigned short* __restrict__ qb,
                                                 const unsigned short* __restrict__ kvb,
                                                 unsigned short* __restrict__ ob)
{
    __shared__ float ks[32][36];
    __shared__ float vs[32][36];
    int bc = blockIdx.x >> 2, h = blockIdx.x & 3;
    int tid = threadIdx.x;

    #pragma unroll
    for (int i = 0; i < 2; ++i) {
        int fid = tid + i * 128;
        int row = fid >> 3, cc = (fid & 7) * 4;
        const unsigned short* kp = kvb + (size_t)(bc * 32 + row) * 256 + h * 32 + cc;
        u16x4 kk = *(const u16x4*)kp;
        u16x4 vv = *(const u16x4*)(kp + 128);
        #pragma unroll
        for (int j = 0; j < 4; ++j) { ks[row][cc + j] = bf2f(kk[j]); vs[row][cc + j] = bf2f(vv[j]); }
    }

    const unsigned short* qp = qb + (size_t)(bc * 128 + tid) * 128 + h * 32;
    float q[32];
    #pragma unroll
    for (int c = 0; c < 4; ++c) {
        u16x8 v = *(const u16x8*)(qp + c * 8);
        #pragma unroll
        for (int j = 0; j < 8; ++j) q[c * 8 + j] = bf2f(v[j]);
    }
    __syncthreads();

    float sc[32];
    #pragma unroll
    for (int tk = 0; tk < 32; ++tk) {
        float d = 0.0f;
        #pragma unroll
        for (int i = 0; i < 32; ++i) d += q[i] * ks[tk][i];
        sc[tk] = d * ATT_SCALE;
    }
    float mx = -1e30f;
    #pragma unroll
    for (int tk = 0; tk < 32; ++tk) mx = fmaxf(mx, sc[tk]);
    float den = 0.0f;
    #pragma unroll
    for (int tk = 0; tk < 32; ++tk) { sc[tk] = __expf(sc[tk] - mx); den += sc[tk]; }
    float inv = 1.0f / den;

    float o[32];
    #pragma unroll
    for (int i = 0; i < 32; ++i) o[i] = 0.0f;
    #pragma unroll
    for (int tk = 0; tk < 32; ++tk) {
        float a = sc[tk];
        #pragma unroll
        for (int i = 0; i < 32; ++i) o[i] += a * vs[tk][i];
    }
    unsigned short* op = ob + (size_t)(bc * 128 + tid) * 128 + h * 32;
    #pragma unroll
    for (int c = 0; c < 4; ++c) {
        u16x8 v;
        #pragma unroll
        for (int j = 0; j < 8; ++j) v[j] = f2bf(o[c * 8 + j] * inv);
        *(u16x8*)(op + c * 8) = v;
    }
}

// ---------------------------------------------------------------------------
// addln: one 64-lane wave per row (4 rows/block), lane holds 4 cols.
// MODE 0: x + [hi|lo] -> LN -> x bf16
// MODE 1: x + f       -> LN -> x bf16
// MODE 2: x + f -> LN2 -> LNf -> out f32 (fused tail, f32 precision)
// ---------------------------------------------------------------------------
template<int MODE>
__global__ __launch_bounds__(256) void addln(
    const unsigned short* __restrict__ x,
    const unsigned short* __restrict__ r1,
    const unsigned short* __restrict__ r2,
    const float* __restrict__ g, const float* __restrict__ b,
    const float* __restrict__ g2, const float* __restrict__ b2,
    unsigned short* __restrict__ xout, float* __restrict__ fout)
{
    size_t row = (size_t)blockIdx.x * 4 + (threadIdx.x >> 6);
    int l = threadIdx.x & 63;
    u16x4 xv = *(const u16x4*)(x + row * 256 + l * 4);
    f32x4 v;
    #pragma unroll
    for (int j = 0; j < 4; ++j) v[j] = bf2f(xv[j]);
    if (MODE == 0) {
        const unsigned short* rp = (l < 32) ? (r1 + row * 128 + l * 4)
                                            : (r2 + row * 128 + (l - 32) * 4);
        u16x4 rv = *(const u16x4*)rp;
        #pragma unroll
        for (int j = 0; j < 4; ++j) v[j] += bf2f(rv[j]);
    } else {
        u16x4 rv = *(const u16x4*)(r1 + row * 256 + l * 4);
        #pragma unroll
        for (int j = 0; j < 4; ++j) v[j] += bf2f(rv[j]);
    }
    float s = v[0] + v[1] + v[2] + v[3];
    float sq = v[0] * v[0] + v[1] * v[1] + v[2] * v[2] + v[3] * v[3];
    #pragma unroll
    for (int off = 32; off > 0; off >>= 1) { s += __shfl_xor(s, off); sq += __shfl_xor(sq, off); }
    float mean = s * (1.0f / 256.0f);
    float rstd = rsqrtf(sq * (1.0f / 256.0f) - mean * mean + 1e-5f);
    f32x4 gv = *(const f32x4*)(g + l * 4);
    f32x4 bv = *(const f32x4*)(b + l * 4);
    f32x4 o;
    #pragma unroll
    for (int j = 0; j < 4; ++j) o[j] = (v[j] - mean) * rstd * gv[j] + bv[j];
    if (MODE == 2) {
        float s2 = o[0] + o[1] + o[2] + o[3];
        float sq2 = o[0] * o[0] + o[1] * o[1] + o[2] * o[2] + o[3] * o[3];
        #pragma unroll
        for (int off = 32; off > 0; off >>= 1) { s2 += __shfl_xor(s2, off); sq2 += __shfl_xor(sq2, off); }
        float mean2 = s2 * (1.0f / 256.0f);
        float rstd2 = rsqrtf(sq2 * (1.0f / 256.0f) - mean2 * mean2 + 1e-5f);
        f32x4 g2v = *(const f32x4*)(g2 + l * 4);
        f32x4 b2v = *(const f32x4*)(b2 + l * 4);
        f32x4 f;
        #pragma unroll
        for (int j = 0; j < 4; ++j) f[j] = (o[j] - mean2) * rstd2 * g2v[j] + b2v[j];
        *(f32x4*)(fout + row * 256 + l * 4) = f;
    } else {
        u16x4 t;
        #pragma unroll
        for (int j = 0; j < 4; ++j) t[j] = f2bf(o[j]);
        *(u16x4*)(xout + row * 256 + l * 4) = t;
    }
}

// ---------------------------------------------------------------------------
extern "C" void kernel_launch(void* const* d_in, const int* in_sizes, int n_in,
                              void* d_out, int out_size, void* d_ws, size_t ws_size,
                              hipStream_t stream)
{
    (void)in_sizes; (void)n_in; (void)out_size; (void)ws_size;
    const float* tgt   = (const float*)d_in[0];
    const float* Wlq   = (const float*)d_in[1];
    const float* Wlkv  = (const float*)d_in[2];
    const float* Wlp   = (const float*)d_in[3];
    const float* blp   = (const float*)d_in[4];
    const float* Whqkv = (const float*)d_in[5];
    const float* Whp   = (const float*)d_in[6];
    const float* bhp   = (const float*)d_in[7];
    const float* W1    = (const float*)d_in[8];
    const float* b1    = (const float*)d_in[9];
    const float* W2    = (const float*)d_in[10];
    const float* b2    = (const float*)d_in[11];
    const float* ln1g  = (const float*)d_in[12];
    const float* ln1b  = (const float*)d_in[13];
    const float* ln2g  = (const float*)d_in[14];
    const float* ln2b  = (const float*)d_in[15];
    const float* lnfg  = (const float*)d_in[16];
    const float* lnfb  = (const float*)d_in[17];

    unsigned short* wsu = (unsigned short*)d_ws;
    unsigned short* tWhqkv = wsu;             // 2*384*256
    unsigned short* tWhp   = wsu + 196608;    // 2*128*128
    unsigned short* tWlq   = wsu + 229376;    // 2*128*256
    unsigned short* tWlkv  = wsu + 294912;    // 2*256*256
    unsigned short* tWlp   = wsu + 425984;    // 2*128*128
    unsigned short* tW1    = wsu + 458752;    // 2*512*256
    unsigned short* tW2    = wsu + 720896;    // 2*256*512
    unsigned short* x    = wsu + 983040;                 // R*256
    unsigned short* qkv  = x + RT * 256;                 // R*384
    unsigned short* f    = qkv;                          // R*256, aliases qkv (dead after hifi)
    unsigned short* los  = qkv + RT * 256;               // aliases qkv tail
    unsigned short* os   = qkv + RT * 384;               // R*128
    unsigned short* qb   = os;                           // aliases os
    unsigned short* xp   = os + RT * 128;                // 32768*256
    unsigned short* kv   = xp + 32768ull * 256;          // 32768*256
    unsigned short* hi   = kv + 32768ull * 256;          // R*128
    unsigned short* lo   = hi + RT * 128;                // R*128
    unsigned short* hbuf = hi;                           // R*512 (hi/lo dead after addln1)

    wprep<<<dim3(8, 12, 2), 256, 0, stream>>>(Whqkv, tWhqkv, 256, 384);
    wprep<<<dim3(4,  4, 2), 256, 0, stream>>>(Whp,   tWhp,   128, 128);
    wprep<<<dim3(8,  4, 2), 256, 0, stream>>>(Wlq,   tWlq,   256, 128);
    wprep<<<dim3(8,  8, 2), 256, 0, stream>>>(Wlkv,  tWlkv,  256, 256);
    wprep<<<dim3(4,  4, 2), 256, 0, stream>>>(Wlp,   tWlp,   128, 128);
    wprep<<<dim3(8, 16, 2), 256, 0, stream>>>(W1,    tW1,    256, 512);
    wprep<<<dim3(16, 8, 2), 256, 0, stream>>>(W2,    tW2,    512, 256);

    cvt_bf16<<<16384, 256, 0, stream>>>(tgt, x);

    for (int li = 0; li < 2; ++li) {
        // 1. qkv = x @ WhqkvT
        gemm_bb<128, false, false><<<dim3(1024, 3), 256, 0, stream>>>(
            x, 256, tWhqkv + (size_t)li * 98304, nullptr, qkv, 384, 256);
        // 2. hifi window attention -> os
        hifi_attn<<<2048, 256, 0, stream>>>(qkv, os);
        // 3. hi = os @ WhpT + bhp
        gemm_bb<128, true, false><<<dim3(1024, 1), 256, 0, stream>>>(
            os, 128, tWhp + (size_t)li * 16384, bhp + li * 128, hi, 128, 128);
        // 4. qb = x @ WlqT   (qb aliases os — os dead after step 3)
        gemm_bb<128, false, false><<<dim3(1024, 1), 256, 0, stream>>>(
            x, 256, tWlq + (size_t)li * 32768, nullptr, qb, 128, 256);
        // 5. pool
        pool_k<<<4096, 256, 0, stream>>>(x, xp);
        // 6. kv = xp @ WlkvT   (M = 32768)
        gemm_bb<128, false, false><<<dim3(256, 2), 256, 0, stream>>>(
            xp, 256, tWlkv + (size_t)li * 65536, nullptr, kv, 256, 256);
        // 7. lofi attention -> los
        lofi_attn<<<4096, 128, 0, stream>>>(qb, kv, los);
        // 8. lo = los @ WlpT + blp
        gemm_bb<128, true, false><<<dim3(1024, 1), 256, 0, stream>>>(
            los, 128, tWlp + (size_t)li * 16384, blp + li * 128, lo, 128, 128);
        // 9. x = LN(x + [hi|lo])
        addln<0><<<32768, 256, 0, stream>>>(x, hi, lo, ln1g + li * 256, ln1b + li * 256,
                                            nullptr, nullptr, x, nullptr);
        // 10. h = relu(x @ W1T + b1)   (hbuf reuses hi/lo region, dead now)
        gemm_bb<128, true, true><<<dim3(1024, 4), 256, 0, stream>>>(
            x, 256, tW1 + (size_t)li * 131072, b1 + li * 512, hbuf, 512, 256);
        // 11. f = h @ W2T + b2   (f aliases qkv[0:R*256])
        gemm_bb<128, true, false><<<dim3(1024, 2), 256, 0, stream>>>(
            hbuf, 512, tW2 + (size_t)li * 131072, b2 + li * 256, f, 256, 512);
        // 12. x = LN(x + f)  |  layer 1: fused LN2 + final LN -> f32 out
        if (li == 0) {
            addln<1><<<32768, 256, 0, stream>>>(x, f, nullptr, ln2g, ln2b,
                                                nullptr, nullptr, x, nullptr);
        } else {
            addln<2><<<32768, 256, 0, stream>>>(x, f, nullptr, ln2g + 256, ln2b + 256,
                                                lnfg, lnfb, nullptr, (float*)d_out);
        }
    }
}